// Round 2
// baseline (810.942 us; speedup 1.0000x reference)
//
#include <hip/hip_runtime.h>
#include <hip/hip_bf16.h>

typedef unsigned int u32;
typedef unsigned short u16;
using f32x4 = __attribute__((ext_vector_type(4))) float;
using s16x8 = __attribute__((ext_vector_type(8))) short;

#define NB 128
#define NH 8
#define LT 2050   // L + 2
#define ND 10     // DIM

__device__ __forceinline__ u16 f2bf(float x){
  u32 u = __float_as_uint(x);
  u32 r = u + 0x7FFFu + ((u >> 16) & 1u);   // RNE, no NaN handling (no NaNs here)
  return (u16)(r >> 16);
}
__device__ __forceinline__ float bflo(u32 d){ return __uint_as_float(d << 16); }
__device__ __forceinline__ float bfhi(u32 d){ return __uint_as_float(d & 0xFFFF0000u); }

// ---------------------------------------------------------------------------
// P1: depthwise convs -> packed bf16 y rows [b][t][32 shorts]:
//     shorts 0..9 = yq[0..9], 16..25 = yk[0..9], rest zero. 64B rows.
//     Quads are XOR-swizzled by qsel(t) so the consumer's LDS reads spread banks.
__global__ void k_pack_y(const float* __restrict__ Q, const float* __restrict__ Kin,
                         const float* __restrict__ w1, const float* __restrict__ b1,
                         const float* __restrict__ w2, const float* __restrict__ b2,
                         u16* __restrict__ ypack)
{
  int g = blockIdx.x * 256 + threadIdx.x;
  if (g >= NB * LT) return;
  int b = g / LT, t = g - b * LT;
  const float* Qb = Q   + (size_t)b * ND * 2048;
  const float* Kb = Kin + (size_t)b * ND * 2048;
  u32 wq[16];
#pragma unroll
  for (int i = 0; i < 16; i++) wq[i] = 0;
#pragma unroll
  for (int u = 0; u < ND; u++){
    float aq = b1[u], ak = b2[u];
#pragma unroll
    for (int kk = 0; kk < 3; kk++){
      int x = t + kk - 2;                      // padding=2, kernel=3
      if (x >= 0 && x < 2048){
        aq = fmaf(w1[u*3+kk], Qb[u*2048 + x], aq);
        ak = fmaf(w2[u*3+kk], Kb[u*2048 + x], ak);
      }
    }
    u16 hq = f2bf(aq), hk = f2bf(ak);
    wq[u >> 1]       |= ((u32)hq) << ((u & 1) * 16);
    wq[8 + (u >> 1)] |= ((u32)hk) << ((u & 1) * 16);
  }
  u32 qsel = (u32)((t ^ (t >> 2)) & 3);
  uint4* dst = (uint4*)((char*)ypack + ((size_t)b * LT + t) * 64);
  uint4 q0 = make_uint4(wq[0], wq[1], wq[2], wq[3]);
  uint4 q1 = make_uint4(wq[4], 0, 0, 0);
  uint4 q2 = make_uint4(wq[8], wq[9], wq[10], wq[11]);
  uint4 q3 = make_uint4(wq[12], 0, 0, 0);
  dst[0 ^ qsel] = q0; dst[1 ^ qsel] = q1; dst[2 ^ qsel] = q2; dst[3 ^ qsel] = q3;
}

// ---------------------------------------------------------------------------
// P2a: WC[o][c] = sum_d W_V[o,d] * v_fc_w[d,c]  (c=10 -> bias combine with v_fc_b)
__global__ void k_wc(const float* __restrict__ Wv, const float* __restrict__ vfw,
                     const float* __restrict__ vfb, float* __restrict__ WCbc)
{
  int id = blockIdx.x * 256 + threadIdx.x;
  if (id >= 512 * 11) return;
  int o = id / 11, c = id - o * 11;
  const float* wr = Wv + (size_t)o * 512;
  float s = 0.f;
  if (c < 10){ for (int d = 0; d < 512; d++) s = fmaf(wr[d], vfw[d*10 + c], s); }
  else       { for (int d = 0; d < 512; d++) s = fmaf(wr[d], vfb[d], s); }
  WCbc[id] = s;
}

// ---------------------------------------------------------------------------
// P2b: vsT[b][h][lc][j] = v[b, lc, h*64+j] = bc[o] + sum_c V[b,lc,c]*WC[o,c]   (bf16)
__global__ void k_vst(const float* __restrict__ V, const float* __restrict__ WCbc,
                      u16* __restrict__ vsT)
{
  int g = blockIdx.x * 256 + threadIdx.x;
  if (g >= NB * NH * 20 * 64) return;
  int j  = g & 63;
  int lc = (g >> 6) % 20;
  int hh = (g / (64 * 20)) & 7;
  int b  = g / (64 * 20 * 8);
  int o  = hh * 64 + j;
  const float* wc = WCbc + o * 11;
  const float* vr = V + ((size_t)b * 20 + lc) * 10;
  float s = wc[10];
#pragma unroll
  for (int c = 0; c < 10; c++) s = fmaf(vr[c], wc[c], s);
  vsT[g] = f2bf(s);
}

// ---------------------------------------------------------------------------
// P2c: W_O -> bf16 (same [d][o] layout)
__global__ void k_wobf(const float* __restrict__ Wo, u16* __restrict__ Wobf){
  int g = blockIdx.x * 256 + threadIdx.x;
  if (g < 512 * 512) Wobf[g] = f2bf(Wo[g]);
}

// ---------------------------------------------------------------------------
// S: per (b,h) block: generate Gram operands from y on the fly, MFMA Gram over
//    K=2050, scores(+prev,/8) -> softmax (in-register) -> attn out,
//    context = attn @ v_s via MFMA, scatter ctx2 (bf16) for the output GEMM.
__launch_bounds__(256, 1)
__global__ void k_scores(const u16* __restrict__ ypack,
                         const float* __restrict__ pw1, const float* __restrict__ pb1,
                         const float* __restrict__ pw2, const float* __restrict__ pb2,
                         const float* __restrict__ prev,
                         const u16* __restrict__ vsT,
                         float* __restrict__ attn_out, float* __restrict__ scores_out,
                         u16* __restrict__ ctx2)
{
  // LDS: y packed 131200B | A tile [64][72]bf16 9216B | B tile 9216B = 149632B
  __shared__ uint4 smem_[9352];
  char* sm = (char*)smem_;
  char* Al = sm + 131200;
  char* Bl = sm + 140416;

  int b    = blockIdx.x & (NB - 1);   // same-b blocks land on same XCD (bid % 8 pattern)
  int h    = blockIdx.x >> 7;
  int tid  = threadIdx.x;
  int lane = tid & 63, w = tid >> 6;

  { // stage packed y for this batch (swizzle already applied in global layout)
    const uint4* src = (const uint4*)((const char*)ypack + (size_t)b * (LT * 64));
    uint4* dstl = (uint4*)sm;
    for (int i = tid; i < 8200; i += 256) dstl[i] = src[i];
  }
  __syncthreads();

  f32x4 acc0 = {0,0,0,0}, acc1 = {0,0,0,0}, acc2 = {0,0,0,0}, acc3 = {0,0,0,0};

  for (int kt = 0; kt < 33; kt++){            // K tiles of 64 chunks (2112 >= 2050)
    // ---- generation: wave w fills kk in [16w, 16w+16) of A/B tiles
    for (int m = 0; m < 16; m++){
      int kk = w * 16 + m;
      int k  = kt * 64 + kk;
      float aval = 0.f, bval = 0.f;
      if (k < LT){
        int base = k * 512 + h * 64;
        int c0 = base / LT;
        int t0 = base - c0 * LT;
        int c0s = __builtin_amdgcn_readfirstlane(c0);
        int t0s = __builtin_amdgcn_readfirstlane(t0);
        int t  = t0s + lane;
        int tw = (t >= LT) ? (t - LT) : t;
        u32 qo = (u32)(((tw ^ (tw >> 2)) & 3) << 4);
        const char* yr = sm + tw * 64;
        uint4 dq  = *(const uint4*)(yr + ( 0u ^ qo));
        u32  dqh  = *(const u32*) (yr + (16u ^ qo));
        uint4 dk4 = *(const uint4*)(yr + (32u ^ qo));
        u32  dkh  = *(const u32*) (yr + (48u ^ qo));
        float yqv[10], ykv[10];
        yqv[0]=bflo(dq.x);  yqv[1]=bfhi(dq.x);  yqv[2]=bflo(dq.y);  yqv[3]=bfhi(dq.y);
        yqv[4]=bflo(dq.z);  yqv[5]=bfhi(dq.z);  yqv[6]=bflo(dq.w);  yqv[7]=bfhi(dq.w);
        yqv[8]=bflo(dqh);   yqv[9]=bfhi(dqh);
        ykv[0]=bflo(dk4.x); ykv[1]=bfhi(dk4.x); ykv[2]=bflo(dk4.y); ykv[3]=bfhi(dk4.y);
        ykv[4]=bflo(dk4.z); ykv[5]=bfhi(dk4.z); ykv[6]=bflo(dk4.w); ykv[7]=bfhi(dk4.w);
        ykv[8]=bflo(dkh);   ykv[9]=bfhi(dkh);
        if (t0s <= LT - 64){                   // no c-boundary inside chunk (97%)
          aval = pb1[c0s]; bval = pb2[c0s];
#pragma unroll
          for (int u = 0; u < 10; u++){
            aval = fmaf(pw1[c0s*10 + u], yqv[u], aval);
            bval = fmaf(pw2[c0s*10 + u], ykv[u], bval);
          }
        } else {
          int c1s = c0s + 1;                   // never exceeds 511 (no wrap at c=511)
          bool wb = (t >= LT);
          aval = wb ? pb1[c1s] : pb1[c0s];
          bval = wb ? pb2[c1s] : pb2[c0s];
#pragma unroll
          for (int u = 0; u < 10; u++){
            float w1u = wb ? pw1[c1s*10 + u] : pw1[c0s*10 + u];
            float w2u = wb ? pw2[c1s*10 + u] : pw2[c0s*10 + u];
            aval = fmaf(w1u, yqv[u], aval);
            bval = fmaf(w2u, ykv[u], bval);
          }
        }
      }
      *(u16*)(Al + lane * 144 + kk * 2) = f2bf(aval);
      *(u16*)(Bl + lane * 144 + kk * 2) = f2bf(bval);
    }
    __syncthreads();
    // ---- Gram MFMA: wave w owns rows [16w,16w+16), cols 0..63 (4 frags)
    {
      const char* pa = Al + (16*w + (lane & 15)) * 144 + ((lane >> 4) * 16);
      const char* pb = Bl + (lane & 15) * 144 + ((lane >> 4) * 16);
#pragma unroll
      for (int ks = 0; ks < 2; ks++){
        s16x8 av  = *(const s16x8*)(pa + ks * 64);
        s16x8 b0  = *(const s16x8*)(pb + ks * 64);
        s16x8 b1v = *(const s16x8*)(pb + ks * 64 + 16 * 144);
        s16x8 b2v = *(const s16x8*)(pb + ks * 64 + 32 * 144);
        s16x8 b3v = *(const s16x8*)(pb + ks * 64 + 48 * 144);
        acc0 = __builtin_amdgcn_mfma_f32_16x16x32_bf16(av, b0,  acc0, 0, 0, 0);
        acc1 = __builtin_amdgcn_mfma_f32_16x16x32_bf16(av, b1v, acc1, 0, 0, 0);
        acc2 = __builtin_amdgcn_mfma_f32_16x16x32_bf16(av, b2v, acc2, 0, 0, 0);
        acc3 = __builtin_amdgcn_mfma_f32_16x16x32_bf16(av, b3v, acc3, 0, 0, 0);
      }
    }
    __syncthreads();
  }

  // ---- epilogue: y region is dead; alias attn_lds (9216B) + vsT_lds (4608B)
  char* attnl = sm;
  char* vstl  = sm + 9216;

  { // stage v_s^T (rows lc 0..19 real, 20..31 zero) as bf16 [32][72]
    int idx = tid;              // 256 slots of 16B: 32 rows x 8
    int row = idx >> 3, c8 = idx & 7;
    uint4 v = make_uint4(0, 0, 0, 0);
    if (row < 20)
      v = *(const uint4*)((const char*)vsT + ((size_t)(b*NH + h)) * 2560 + row * 128 + c8 * 16);
    *(uint4*)(vstl + row * 144 + c8 * 16) = v;
  }

  int ib = 16 * w + ((lane >> 4) << 2);        // C/D row base: (lane>>4)*4 + reg
  int jc = lane & 15;                          // C/D col
  const float* prevb = prev       + ((size_t)(b*NH + h)) * 4096;
  float*       scob  = scores_out + ((size_t)(b*NH + h)) * 4096;
  float*       atob  = attn_out   + ((size_t)(b*NH + h)) * 4096;

  f32x4 accs[4] = {acc0, acc1, acc2, acc3};
  float sc[4][4];
#pragma unroll
  for (int r = 0; r < 4; r++)
#pragma unroll
    for (int f = 0; f < 4; f++)
      sc[r][f] = accs[f][r] * 0.125f + prevb[(ib + r) * 64 + f * 16 + jc];

#pragma unroll
  for (int r = 0; r < 4; r++){
    float mx = fmaxf(fmaxf(sc[r][0], sc[r][1]), fmaxf(sc[r][2], sc[r][3]));
#pragma unroll
    for (int s = 1; s < 16; s <<= 1) mx = fmaxf(mx, __shfl_xor(mx, s, 64));
    float e[4], ssum = 0.f;
#pragma unroll
    for (int f = 0; f < 4; f++){ e[f] = __expf(sc[r][f] - mx); ssum += e[f]; }
#pragma unroll
    for (int s = 1; s < 16; s <<= 1) ssum += __shfl_xor(ssum, s, 64);
    float inv = 1.0f / ssum;
#pragma unroll
    for (int f = 0; f < 4; f++){
      int i = ib + r, j = f * 16 + jc;
      float at = e[f] * inv;
      scob[i * 64 + j] = sc[r][f];
      atob[i * 64 + j] = at;
      *(u16*)(attnl + i * 144 + j * 2) = f2bf(at);
    }
  }
  __syncthreads();

  // ---- context = attn @ v_s  (M=64 rows per wave-quadrant, N=32 (20 valid), K=64)
  f32x4 ca0 = {0,0,0,0}, ca1 = {0,0,0,0};
#pragma unroll
  for (int ks = 0; ks < 2; ks++){
    s16x8 av  = *(const s16x8*)(attnl + (16*w + (lane & 15)) * 144 + ks * 64 + ((lane >> 4) * 16));
    s16x8 b0  = *(const s16x8*)(vstl  + (lane & 15) * 144        + ks * 64 + ((lane >> 4) * 16));
    s16x8 b1v = *(const s16x8*)(vstl  + (16 + (lane & 15)) * 144 + ks * 64 + ((lane >> 4) * 16));
    ca0 = __builtin_amdgcn_mfma_f32_16x16x32_bf16(av, b0,  ca0, 0, 0, 0);
    ca1 = __builtin_amdgcn_mfma_f32_16x16x32_bf16(av, b1v, ca1, 0, 0, 0);
  }
  // scatter ctx2[b, dv*160 + h*20 + lc] (= row-major [b][lp][o] of context2)
  u16* ctxb = ctx2 + (size_t)b * 10240;
#pragma unroll
  for (int f = 0; f < 2; f++){
    f32x4 cv = f ? ca1 : ca0;
#pragma unroll
    for (int r = 0; r < 4; r++){
      int i = ib + r, lc = f * 16 + jc;
      if (lc < 20) ctxb[i * 160 + h * 20 + lc] = f2bf(cv[r]);
    }
  }
}

// ---------------------------------------------------------------------------
// O: output[b] = ctx2[b] (20x512, pad to 32) @ W_O^T  via MFMA, K=512
__launch_bounds__(256)
__global__ void k_out(const u16* __restrict__ ctx2, const u16* __restrict__ Wobf,
                      float* __restrict__ outp)
{
  __shared__ u16 ctxl[32 * 520];
  int b = blockIdx.x, tid = threadIdx.x;
  for (int idx = tid; idx < 2048; idx += 256){
    int row = idx >> 6, c8 = idx & 63;
    uint4 v = make_uint4(0, 0, 0, 0);
    if (row < 20)
      v = *(const uint4*)((const char*)ctx2 + (size_t)b * 20480 + row * 1024 + c8 * 16);
    *(uint4*)((char*)ctxl + row * 1040 + c8 * 16) = v;
  }
  __syncthreads();
  int lane = tid & 63, w = tid >> 6;
  f32x4 acc[2][8];
#pragma unroll
  for (int m2 = 0; m2 < 2; m2++)
#pragma unroll
    for (int n = 0; n < 8; n++) acc[m2][n] = (f32x4){0,0,0,0};

  for (int ks = 0; ks < 16; ks++){
    s16x8 a0 = *(const s16x8*)((char*)ctxl + (lane & 15) * 1040        + ks * 64 + ((lane >> 4) * 16));
    s16x8 a1 = *(const s16x8*)((char*)ctxl + (16 + (lane & 15)) * 1040 + ks * 64 + ((lane >> 4) * 16));
#pragma unroll
    for (int n = 0; n < 8; n++){
      int d = w * 128 + n * 16 + (lane & 15);
      s16x8 bb = *(const s16x8*)((const char*)Wobf + (size_t)d * 1024 + ks * 64 + ((lane >> 4) * 16));
      acc[0][n] = __builtin_amdgcn_mfma_f32_16x16x32_bf16(a0, bb, acc[0][n], 0, 0, 0);
      acc[1][n] = __builtin_amdgcn_mfma_f32_16x16x32_bf16(a1, bb, acc[1][n], 0, 0, 0);
    }
  }
  float* ob = outp + (size_t)b * 10240;
#pragma unroll
  for (int m2 = 0; m2 < 2; m2++){
    int lp0 = m2 * 16 + ((lane >> 4) << 2);
    if (lp0 >= 20) continue;
#pragma unroll
    for (int n = 0; n < 8; n++){
      int d = w * 128 + n * 16 + (lane & 15);
#pragma unroll
      for (int r = 0; r < 4; r++){
        int lp = lp0 + r;
        if (lp < 20) ob[lp * 512 + d] = acc[m2][n][r];
      }
    }
  }
}

// ---------------------------------------------------------------------------
extern "C" void kernel_launch(void* const* d_in, const int* in_sizes, int n_in,
                              void* d_out, int out_size, void* d_ws, size_t ws_size,
                              hipStream_t stream)
{
  (void)in_sizes; (void)n_in; (void)out_size; (void)ws_size;
  const float* Q      = (const float*)d_in[0];
  const float* K      = (const float*)d_in[1];
  const float* V      = (const float*)d_in[2];
  const float* prev   = (const float*)d_in[3];
  const float* c1w    = (const float*)d_in[4];
  const float* c1b    = (const float*)d_in[5];
  const float* c1pw   = (const float*)d_in[6];
  const float* c1pb   = (const float*)d_in[7];
  const float* c2w    = (const float*)d_in[8];
  const float* c2b    = (const float*)d_in[9];
  const float* c2pw   = (const float*)d_in[10];
  const float* c2pb   = (const float*)d_in[11];
  const float* vfw    = (const float*)d_in[12];
  const float* vfb    = (const float*)d_in[13];
  const float* Wv     = (const float*)d_in[14];
  const float* Wo     = (const float*)d_in[15];

  char* ws = (char*)d_ws;
  u16*   ypack = (u16*)(ws + 0);            // 16,793,600 B
  float* WCbc  = (float*)(ws + 16793600);   //     22,528 B
  u16*   vsT   = (u16*)(ws + 16816128);     //  2,621,440 B
  u16*   Wobf  = (u16*)(ws + 19437568);     //    524,288 B
  u16*   ctx2  = (u16*)(ws + 19961856);     //  2,621,440 B  (total ~22.6 MB)

  float* outp     = (float*)d_out;
  float* attn_o   = outp + 1310720;
  float* scores_o = outp + 5505024;

  k_pack_y<<<dim3(1025), dim3(256), 0, stream>>>(Q, K, c1w, c1b, c2w, c2b, ypack);
  k_wc    <<<dim3(22),   dim3(256), 0, stream>>>(Wv, vfw, vfb, WCbc);
  k_vst   <<<dim3(5120), dim3(256), 0, stream>>>(V, WCbc, vsT);
  k_wobf  <<<dim3(1024), dim3(256), 0, stream>>>(Wo, Wobf);
  k_scores<<<dim3(1024), dim3(256), 0, stream>>>(ypack, c1pw, c1pb, c2pw, c2pb,
                                                 prev, vsT, attn_o, scores_o, ctx2);
  k_out   <<<dim3(128),  dim3(256), 0, stream>>>(ctx2, Wobf, outp);
}

// Round 6
// 497.243 us; speedup vs baseline: 1.6309x; 1.6309x over previous
//
#include <hip/hip_runtime.h>
#include <hip/hip_bf16.h>

typedef unsigned int u32;
typedef unsigned short u16;
using f32x4 = __attribute__((ext_vector_type(4))) float;
using s16x8 = __attribute__((ext_vector_type(8))) short;

#define NB 128
#define NH 8
#define LT 2050   // L + 2
#define ND 10     // DIM

__device__ __forceinline__ u16 f2bf(float x){
  u32 u = __float_as_uint(x);
  u32 r = u + 0x7FFFu + ((u >> 16) & 1u);   // RNE
  return (u16)(r >> 16);
}
__device__ __forceinline__ float bflo(u32 d){ return __uint_as_float(d << 16); }
__device__ __forceinline__ float bfhi(u32 d){ return __uint_as_float(d & 0xFFFF0000u); }

// ---------------------------------------------------------------------------
// P1: depthwise convs -> bf16 y tables, per b: [q: 2050 rows x 24B][k: same]
//     (24B stride => 6t mod 32 bank pattern: conflict-free b64 reads in consumer)
__global__ void k_pack_y(const float* __restrict__ Q, const float* __restrict__ Kin,
                         const float* __restrict__ w1, const float* __restrict__ b1,
                         const float* __restrict__ w2, const float* __restrict__ b2,
                         u16* __restrict__ ypack)
{
  int g = blockIdx.x * 256 + threadIdx.x;
  if (g >= NB * LT) return;
  int b = g / LT, t = g - b * LT;
  const float* Qb = Q   + (size_t)b * ND * 2048;
  const float* Kb = Kin + (size_t)b * ND * 2048;
  u32 wq[5], wk[5];
#pragma unroll
  for (int i = 0; i < 5; i++){ wq[i] = 0; wk[i] = 0; }
#pragma unroll
  for (int u = 0; u < ND; u++){
    float aq = b1[u], ak = b2[u];
#pragma unroll
    for (int kk = 0; kk < 3; kk++){
      int x = t + kk - 2;                      // padding=2, kernel=3
      if (x >= 0 && x < 2048){
        aq = fmaf(w1[u*3+kk], Qb[u*2048 + x], aq);
        ak = fmaf(w2[u*3+kk], Kb[u*2048 + x], ak);
      }
    }
    wq[u >> 1] |= ((u32)f2bf(aq)) << ((u & 1) * 16);
    wk[u >> 1] |= ((u32)f2bf(ak)) << ((u & 1) * 16);
  }
  char* basep = (char*)ypack + (size_t)b * 98400;
  char* qr = basep + t * 24;
  char* kr = basep + 49200 + t * 24;
  *(uint2*)(qr)      = make_uint2(wq[0], wq[1]);
  *(uint2*)(qr + 8)  = make_uint2(wq[2], wq[3]);
  *(u32*) (qr + 16)  = wq[4];
  *(u32*) (qr + 20)  = 0;
  *(uint2*)(kr)      = make_uint2(wk[0], wk[1]);
  *(uint2*)(kr + 8)  = make_uint2(wk[2], wk[3]);
  *(u32*) (kr + 16)  = wk[4];
  *(u32*) (kr + 20)  = 0;
}

// ---------------------------------------------------------------------------
// P2a: WC[o][c] = sum_d W_V[o,d] * v_fc_w[d,c]  (c=10 -> bias combine with v_fc_b)
__global__ void k_wc(const float* __restrict__ Wv, const float* __restrict__ vfw,
                     const float* __restrict__ vfb, float* __restrict__ WCbc)
{
  int id = blockIdx.x * 256 + threadIdx.x;
  if (id >= 512 * 11) return;
  int o = id / 11, c = id - o * 11;
  const float* wr = Wv + (size_t)o * 512;
  float s = 0.f;
  if (c < 10){ for (int d = 0; d < 512; d++) s = fmaf(wr[d], vfw[d*10 + c], s); }
  else       { for (int d = 0; d < 512; d++) s = fmaf(wr[d], vfb[d], s); }
  WCbc[id] = s;
}

// ---------------------------------------------------------------------------
// P2b: vsT[b][h][lc][j] = v[b, lc, h*64+j]   (bf16)
__global__ void k_vst(const float* __restrict__ V, const float* __restrict__ WCbc,
                      u16* __restrict__ vsT)
{
  int g = blockIdx.x * 256 + threadIdx.x;
  if (g >= NB * NH * 20 * 64) return;
  int j  = g & 63;
  int lc = (g >> 6) % 20;
  int hh = (g / (64 * 20)) & 7;
  int b  = g / (64 * 20 * 8);
  int o  = hh * 64 + j;
  const float* wc = WCbc + o * 11;
  const float* vr = V + ((size_t)b * 20 + lc) * 10;
  float s = wc[10];
#pragma unroll
  for (int c = 0; c < 10; c++) s = fmaf(vr[c], wc[c], s);
  vsT[g] = f2bf(s);
}

// ---------------------------------------------------------------------------
// P2c: W_O -> bf16
__global__ void k_wobf(const float* __restrict__ Wo, u16* __restrict__ Wobf){
  int g = blockIdx.x * 256 + threadIdx.x;
  if (g < 512 * 512) Wobf[g] = f2bf(Wo[g]);
}

// ---------------------------------------------------------------------------
// S: per (b,h): on-the-fly Gram operands from LDS y, double-buffered tiles,
//    8 waves = rows(4 quads) x cols(2 halves). Softmax via LDS half-merge.
// LDS map (bytes):
//   0      yq   [2050 x 24]          49200
//   49200  yk   [2050 x 24]          49200
//   98400  Al0  [64 x 144]            9216   (epilogue: Atl attn tile)
//   107616 Bl0  [64 x 144]            9216
//   116832 Al1                        9216
//   126048 Bl1                        9216   -> total 135264
//   epilogue aliases: vstl @17408 [32x144], Emax @22016 [2][64]f32, Esum @22528
__launch_bounds__(512, 1)
__global__ void k_scores(const u16* __restrict__ ypack,
                         const float* __restrict__ pw1, const float* __restrict__ pb1,
                         const float* __restrict__ pw2, const float* __restrict__ pb2,
                         const float* __restrict__ prev,
                         const u16* __restrict__ vsT,
                         float* __restrict__ attn_out, float* __restrict__ scores_out,
                         u16* __restrict__ ctx2)
{
  __shared__ uint4 smem_[8454];           // 135264 B
  char* sm  = (char*)smem_;
  char* Al0 = sm + 98400;
  char* Bl0 = sm + 107616;
  char* Al1 = sm + 116832;
  char* Bl1 = sm + 126048;

  int b    = blockIdx.x & (NB - 1);       // 8 h-blocks of same b -> same XCD
  int h    = blockIdx.x >> 7;
  int tid  = threadIdx.x;
  int lane = tid & 63, w = tid >> 6;      // 8 waves
  int rw   = w & 3, cw = w >> 2;          // row-quad, col-half

  { // stage y (98400 B contiguous per b) as uint4, stride-1 (conflict-free)
    const uint4* src = (const uint4*)((const char*)ypack + (size_t)b * 98400);
    uint4* dstl = (uint4*)sm;
    for (int i = tid; i < 6150; i += 512) dstl[i] = src[i];
  }

  // gen: wave w fills kk in [8w, 8w+8) for one K-tile; packed b128 writes
  auto gen = [&](int ktile, char* Ap, char* Bp){
    u32 apk[4] = {0,0,0,0}, bpk[4] = {0,0,0,0};
#pragma unroll
    for (int m = 0; m < 8; m++){
      int kk = 8 * w + m;
      int k  = ktile * 64 + kk;
      float aval = 0.f, bval = 0.f;
      if (k < LT){
        int base = k * 512 + h * 64;
        int c0 = base / LT;
        int t0 = base - c0 * LT;
        int c0s = __builtin_amdgcn_readfirstlane(c0);
        int t0s = __builtin_amdgcn_readfirstlane(t0);
        int t  = t0s + lane;
        int tw = (t >= LT) ? (t - LT) : t;
        const char* yq = sm + tw * 24;
        const char* yk = sm + 49200 + tw * 24;
        uint2 q01 = *(const uint2*)(yq);
        uint2 q23 = *(const uint2*)(yq + 8);
        u32   q4  = *(const u32*) (yq + 16);
        uint2 k01 = *(const uint2*)(yk);
        uint2 k23 = *(const uint2*)(yk + 8);
        u32   k4  = *(const u32*) (yk + 16);
        float yqv[10] = {bflo(q01.x),bfhi(q01.x),bflo(q01.y),bfhi(q01.y),
                         bflo(q23.x),bfhi(q23.x),bflo(q23.y),bfhi(q23.y),
                         bflo(q4),  bfhi(q4)};
        float ykv[10] = {bflo(k01.x),bfhi(k01.x),bflo(k01.y),bfhi(k01.y),
                         bflo(k23.x),bfhi(k23.x),bflo(k23.y),bfhi(k23.y),
                         bflo(k4),  bfhi(k4)};
        if (t0s <= LT - 64){                 // no c-boundary inside chunk (97%)
          aval = pb1[c0s]; bval = pb2[c0s];
#pragma unroll
          for (int u = 0; u < 10; u++){
            aval = fmaf(pw1[c0s*10 + u], yqv[u], aval);
            bval = fmaf(pw2[c0s*10 + u], ykv[u], bval);
          }
        } else {
          int c1s = c0s + 1;
          bool wb = (t >= LT);
          aval = wb ? pb1[c1s] : pb1[c0s];
          bval = wb ? pb2[c1s] : pb2[c0s];
#pragma unroll
          for (int u = 0; u < 10; u++){
            float w1u = wb ? pw1[c1s*10 + u] : pw1[c0s*10 + u];
            float w2u = wb ? pw2[c1s*10 + u] : pw2[c0s*10 + u];
            aval = fmaf(w1u, yqv[u], aval);
            bval = fmaf(w2u, ykv[u], bval);
          }
        }
      }
      apk[m >> 1] |= ((u32)f2bf(aval)) << ((m & 1) * 16);
      bpk[m >> 1] |= ((u32)f2bf(bval)) << ((m & 1) * 16);
    }
    *(uint4*)(Ap + lane * 144 + 16 * w) = make_uint4(apk[0], apk[1], apk[2], apk[3]);
    *(uint4*)(Bp + lane * 144 + 16 * w) = make_uint4(bpk[0], bpk[1], bpk[2], bpk[3]);
  };

  __syncthreads();                          // y staged
  gen(0, Al0, Bl0);
  __syncthreads();

  f32x4 acc0 = {0,0,0,0}, acc1 = {0,0,0,0};
  char* Ac = Al0; char* Bc = Bl0; char* An = Al1; char* Bn = Bl1;

  for (int kt = 0; kt < 33; kt++){
    if (kt < 32) gen(kt + 1, An, Bn);
    {
      const char* pa = Ac + (16*rw + (lane & 15)) * 144 + ((lane >> 4) * 16);
      const char* pb = Bc + (32*cw + (lane & 15)) * 144 + ((lane >> 4) * 16);
#pragma unroll
      for (int ks = 0; ks < 2; ks++){
        s16x8 av  = *(const s16x8*)(pa + ks * 64);
        s16x8 b0  = *(const s16x8*)(pb + ks * 64);
        s16x8 b1v = *(const s16x8*)(pb + ks * 64 + 16 * 144);
        acc0 = __builtin_amdgcn_mfma_f32_16x16x32_bf16(av, b0,  acc0, 0, 0, 0);
        acc1 = __builtin_amdgcn_mfma_f32_16x16x32_bf16(av, b1v, acc1, 0, 0, 0);
      }
    }
    char* ts;
    ts = Ac; Ac = An; An = ts;
    ts = Bc; Bc = Bn; Bn = ts;
    __syncthreads();
  }

  // ---- epilogue (y region dead)
  char*  vstl = sm + 17408;                 // [32][144] bf16
  float* Emax = (float*)(sm + 22016);       // [2][64]
  float* Esum = (float*)(sm + 22528);       // [2][64]
  char*  Atl  = Al0;                        // attn bf16 tile [64][144]

  if (tid < 256){                           // stage v_s^T rows (20 real, pad 32)
    int row = tid >> 3, c8 = tid & 7;
    uint4 v = make_uint4(0, 0, 0, 0);
    if (row < 20)
      v = *(const uint4*)((const char*)vsT + ((size_t)(b*NH + h)) * 2560 + row * 128 + c8 * 16);
    *(uint4*)(vstl + row * 144 + c8 * 16) = v;
  }

  int ib = 16 * rw + ((lane >> 4) << 2);    // C/D row base
  int jb = 32 * cw + (lane & 15);           // C/D col base (this wave's half)
  const float* prevb = prev       + ((size_t)(b*NH + h)) * 4096;
  float*       scob  = scores_out + ((size_t)(b*NH + h)) * 4096;
  float*       atob  = attn_out   + ((size_t)(b*NH + h)) * 4096;

  f32x4 accs[2] = {acc0, acc1};
  float sc[4][2];
#pragma unroll
  for (int r = 0; r < 4; r++)
#pragma unroll
    for (int f = 0; f < 2; f++)
      sc[r][f] = accs[f][r] * 0.125f + prevb[(ib + r) * 64 + jb + f * 16];

  // per-row partial max over this wave's 32 cols
  float pm[4];
#pragma unroll
  for (int r = 0; r < 4; r++) pm[r] = fmaxf(sc[r][0], sc[r][1]);
#pragma unroll
  for (int s = 1; s < 16; s <<= 1)
#pragma unroll
    for (int r = 0; r < 4; r++) pm[r] = fmaxf(pm[r], __shfl_xor(pm[r], s, 64));
  if ((lane & 15) == 0){
#pragma unroll
    for (int r = 0; r < 4; r++) Emax[cw * 64 + ib + r] = pm[r];
  }
  // scores to global while waiting
#pragma unroll
  for (int r = 0; r < 4; r++)
#pragma unroll
    for (int f = 0; f < 2; f++)
      scob[(ib + r) * 64 + jb + f * 16] = sc[r][f];
  __syncthreads();

  float e[4][2], ps[4];
#pragma unroll
  for (int r = 0; r < 4; r++){
    float m2 = fmaxf(Emax[ib + r], Emax[64 + ib + r]);
    e[r][0] = __expf(sc[r][0] - m2);
    e[r][1] = __expf(sc[r][1] - m2);
    ps[r] = e[r][0] + e[r][1];
  }
#pragma unroll
  for (int s = 1; s < 16; s <<= 1)
#pragma unroll
    for (int r = 0; r < 4; r++) ps[r] += __shfl_xor(ps[r], s, 64);
  if ((lane & 15) == 0){
#pragma unroll
    for (int r = 0; r < 4; r++) Esum[cw * 64 + ib + r] = ps[r];
  }
  __syncthreads();

#pragma unroll
  for (int r = 0; r < 4; r++){
    float inv = 1.0f / (Esum[ib + r] + Esum[64 + ib + r]);
#pragma unroll
    for (int f = 0; f < 2; f++){
      float at = e[r][f] * inv;
      int i = ib + r, j = jb + f * 16;
      atob[i * 64 + j] = at;
      *(u16*)(Atl + i * 144 + j * 2) = f2bf(at);
    }
  }
  __syncthreads();

  // ---- context = attn @ v_s : wave w -> rows [16rw..+16), v cols [16cw..+16)
  f32x4 ca = {0,0,0,0};
  {
    const char* pa = Atl  + (16*rw + (lane & 15)) * 144 + ((lane >> 4) * 16);
    const char* pv = vstl + (16*cw + (lane & 15)) * 144 + ((lane >> 4) * 16);
#pragma unroll
    for (int ks = 0; ks < 2; ks++){
      s16x8 av = *(const s16x8*)(pa + ks * 64);
      s16x8 bv = *(const s16x8*)(pv + ks * 64);
      ca = __builtin_amdgcn_mfma_f32_16x16x32_bf16(av, bv, ca, 0, 0, 0);
    }
  }
  u16* ctxb = ctx2 + (size_t)b * 10240;
  int lc = 16 * cw + (lane & 15);
  if (lc < 20){
#pragma unroll
    for (int r = 0; r < 4; r++)
      ctxb[(ib + r) * 160 + h * 20 + lc] = f2bf(ca[r]);
  }
}

// ---------------------------------------------------------------------------
// O: output[b] = ctx2[b] (20x512, pad 32) @ W_O^T via MFMA, K=512
__launch_bounds__(256)
__global__ void k_out(const u16* __restrict__ ctx2, const u16* __restrict__ Wobf,
                      float* __restrict__ outp)
{
  __shared__ u16 ctxl[32 * 520];
  int b = blockIdx.x, tid = threadIdx.x;
  for (int idx = tid; idx < 2048; idx += 256){
    int row = idx >> 6, c8 = idx & 63;
    uint4 v = make_uint4(0, 0, 0, 0);
    if (row < 20)
      v = *(const uint4*)((const char*)ctx2 + (size_t)b * 20480 + row * 1024 + c8 * 16);
    *(uint4*)((char*)ctxl + row * 1040 + c8 * 16) = v;
  }
  __syncthreads();
  int lane = tid & 63, w = tid >> 6;
  f32x4 acc[2][8];
#pragma unroll
  for (int m2 = 0; m2 < 2; m2++)
#pragma unroll
    for (int n = 0; n < 8; n++) acc[m2][n] = (f32x4){0,0,0,0};

  for (int ks = 0; ks < 16; ks++){
    s16x8 a0 = *(const s16x8*)((char*)ctxl + (lane & 15) * 1040        + ks * 64 + ((lane >> 4) * 16));
    s16x8 a1 = *(const s16x8*)((char*)ctxl + (16 + (lane & 15)) * 1040 + ks * 64 + ((lane >> 4) * 16));
#pragma unroll
    for (int n = 0; n < 8; n++){
      int d = w * 128 + n * 16 + (lane & 15);
      s16x8 bb = *(const s16x8*)((const char*)Wobf + (size_t)d * 1024 + ks * 64 + ((lane >> 4) * 16));
      acc[0][n] = __builtin_amdgcn_mfma_f32_16x16x32_bf16(a0, bb, acc[0][n], 0, 0, 0);
      acc[1][n] = __builtin_amdgcn_mfma_f32_16x16x32_bf16(a1, bb, acc[1][n], 0, 0, 0);
    }
  }
  float* ob = outp + (size_t)b * 10240;
#pragma unroll
  for (int m2 = 0; m2 < 2; m2++){
    int lp0 = m2 * 16 + ((lane >> 4) << 2);
    if (lp0 >= 20) continue;
#pragma unroll
    for (int n = 0; n < 8; n++){
      int d = w * 128 + n * 16 + (lane & 15);
#pragma unroll
      for (int r = 0; r < 4; r++){
        int lp = lp0 + r;
        if (lp < 20) ob[lp * 512 + d] = acc[m2][n][r];
      }
    }
  }
}

// ---------------------------------------------------------------------------
extern "C" void kernel_launch(void* const* d_in, const int* in_sizes, int n_in,
                              void* d_out, int out_size, void* d_ws, size_t ws_size,
                              hipStream_t stream)
{
  (void)in_sizes; (void)n_in; (void)out_size; (void)ws_size;
  const float* Q      = (const float*)d_in[0];
  const float* K      = (const float*)d_in[1];
  const float* V      = (const float*)d_in[2];
  const float* prev   = (const float*)d_in[3];
  const float* c1w    = (const float*)d_in[4];
  const float* c1b    = (const float*)d_in[5];
  const float* c1pw   = (const float*)d_in[6];
  const float* c1pb   = (const float*)d_in[7];
  const float* c2w    = (const float*)d_in[8];
  const float* c2b    = (const float*)d_in[9];
  const float* c2pw   = (const float*)d_in[10];
  const float* c2pb   = (const float*)d_in[11];
  const float* vfw    = (const float*)d_in[12];
  const float* vfb    = (const float*)d_in[13];
  const float* Wv     = (const float*)d_in[14];
  const float* Wo     = (const float*)d_in[15];

  char* ws = (char*)d_ws;
  u16*   ypack = (u16*)(ws + 0);            // 128 * 98400 = 12,595,200 B
  float* WCbc  = (float*)(ws + 12595200);   //     22,528 B
  u16*   vsT   = (u16*)(ws + 12617728);     //  2,621,440 B
  u16*   Wobf  = (u16*)(ws + 15239168);     //    524,288 B
  u16*   ctx2  = (u16*)(ws + 15763456);     //  2,621,440 B (total ~18.4 MB)

  float* outp     = (float*)d_out;
  float* attn_o   = outp + 1310720;
  float* scores_o = outp + 5505024;

  k_pack_y<<<dim3(1025), dim3(256), 0, stream>>>(Q, K, c1w, c1b, c2w, c2b, ypack);
  k_wc    <<<dim3(22),   dim3(256), 0, stream>>>(Wv, vfw, vfb, WCbc);
  k_vst   <<<dim3(5120), dim3(256), 0, stream>>>(V, WCbc, vsT);
  k_wobf  <<<dim3(1024), dim3(256), 0, stream>>>(Wo, Wobf);
  k_scores<<<dim3(1024), dim3(512), 0, stream>>>(ypack, c1pw, c1pb, c2pw, c2pb,
                                                 prev, vsT, attn_o, scores_o, ctx2);
  k_out   <<<dim3(128),  dim3(256), 0, stream>>>(ctx2, Wobf, outp);
}

// Round 8
// 311.151 us; speedup vs baseline: 2.6063x; 1.5981x over previous
//
#include <hip/hip_runtime.h>
#include <hip/hip_bf16.h>
#include <hip/hip_fp16.h>

typedef unsigned int u32;
typedef unsigned short u16;
using f32x4 = __attribute__((ext_vector_type(4))) float;
using s16x8 = __attribute__((ext_vector_type(8))) short;
typedef _Float16 h16x2 __attribute__((ext_vector_type(2)));

#define NB 128
#define NH 8
#define LT 2050   // L + 2
#define ND 10     // DIM

#if defined(__has_builtin)
#if __has_builtin(__builtin_amdgcn_fdot2)
#define HAVE_FDOT2 1
#endif
#endif
#ifndef HAVE_FDOT2
#define HAVE_FDOT2 0
#endif

__device__ __forceinline__ u16 f2bf(float x){
  u32 u = __float_as_uint(x);
  u32 r = u + 0x7FFFu + ((u >> 16) & 1u);   // RNE
  return (u16)(r >> 16);
}
__device__ __forceinline__ u16 f2h(float x){
  return __half_as_ushort(__float2half(x));
}
__device__ __forceinline__ float h2f_lo(u32 v){
  __half_raw r; r.x = (u16)(v & 0xFFFFu); return __half2float(__half(r));
}
__device__ __forceinline__ float h2f_hi(u32 v){
  __half_raw r; r.x = (u16)(v >> 16); return __half2float(__half(r));
}
__device__ __forceinline__ float dot2p(u32 y, u32 w, float acc){
#if HAVE_FDOT2
  return __builtin_amdgcn_fdot2(__builtin_bit_cast(h16x2, y),
                                __builtin_bit_cast(h16x2, w), acc, false);
#else
  return fmaf(h2f_lo(y), h2f_lo(w), fmaf(h2f_hi(y), h2f_hi(w), acc));
#endif
}

// ---------------------------------------------------------------------------
// P1: depthwise convs -> f16-pair y tables, per b: [q: 2050 x 5 u32][k: same]
//     20B row stride => word index 5t+j, gcd(5,32)=1 -> conflict-free b32 LDS reads
__global__ void k_pack_y(const float* __restrict__ Q, const float* __restrict__ Kin,
                         const float* __restrict__ w1, const float* __restrict__ b1,
                         const float* __restrict__ w2, const float* __restrict__ b2,
                         u32* __restrict__ ypack)
{
  int g = blockIdx.x * 256 + threadIdx.x;
  if (g >= NB * LT) return;
  int b = g / LT, t = g - b * LT;
  const float* Qb = Q   + (size_t)b * ND * 2048;
  const float* Kb = Kin + (size_t)b * ND * 2048;
  u32 wq[5], wk[5];
#pragma unroll
  for (int i = 0; i < 5; i++){ wq[i] = 0; wk[i] = 0; }
#pragma unroll
  for (int u = 0; u < ND; u++){
    float aq = b1[u], ak = b2[u];
#pragma unroll
    for (int kk = 0; kk < 3; kk++){
      int x = t + kk - 2;                      // padding=2, kernel=3
      if (x >= 0 && x < 2048){
        aq = fmaf(w1[u*3+kk], Qb[u*2048 + x], aq);
        ak = fmaf(w2[u*3+kk], Kb[u*2048 + x], ak);
      }
    }
    wq[u >> 1] |= ((u32)f2h(aq)) << ((u & 1) * 16);
    wk[u >> 1] |= ((u32)f2h(ak)) << ((u & 1) * 16);
  }
  u32* qr = ypack + (size_t)b * 20500 + t * 5;           // 20500 u32 per b
  u32* kr = qr + 10250;                                  // k half at +41000B
#pragma unroll
  for (int i = 0; i < 5; i++){ qr[i] = wq[i]; kr[i] = wk[i]; }
}

// ---------------------------------------------------------------------------
// P1b: pack projection weights to f16 pairs: wp[c][5] u32
__global__ void k_wpack(const float* __restrict__ pw1, const float* __restrict__ pw2,
                        u32* __restrict__ wp1, u32* __restrict__ wp2)
{
  int id = blockIdx.x * 256 + threadIdx.x;
  if (id >= 512 * 5) return;
  int c = id / 5, u = id - c * 5;
  wp1[id] = (u32)f2h(pw1[c*10 + 2*u]) | ((u32)f2h(pw1[c*10 + 2*u + 1]) << 16);
  wp2[id] = (u32)f2h(pw2[c*10 + 2*u]) | ((u32)f2h(pw2[c*10 + 2*u + 1]) << 16);
}

// ---------------------------------------------------------------------------
// P2a: WC[o][c] = sum_d W_V[o,d] * v_fc_w[d,c]  (c=10 -> bias combine with v_fc_b)
__global__ void k_wc(const float* __restrict__ Wv, const float* __restrict__ vfw,
                     const float* __restrict__ vfb, float* __restrict__ WCbc)
{
  int id = blockIdx.x * 256 + threadIdx.x;
  if (id >= 512 * 11) return;
  int o = id / 11, c = id - o * 11;
  const float* wr = Wv + (size_t)o * 512;
  float s = 0.f;
  if (c < 10){ for (int d = 0; d < 512; d++) s = fmaf(wr[d], vfw[d*10 + c], s); }
  else       { for (int d = 0; d < 512; d++) s = fmaf(wr[d], vfb[d], s); }
  WCbc[id] = s;
}

// ---------------------------------------------------------------------------
// P2b: vsT[b][h][lc][j] = v[b, lc, h*64+j]   (bf16)
__global__ void k_vst(const float* __restrict__ V, const float* __restrict__ WCbc,
                      u16* __restrict__ vsT)
{
  int g = blockIdx.x * 256 + threadIdx.x;
  if (g >= NB * NH * 20 * 64) return;
  int j  = g & 63;
  int lc = (g >> 6) % 20;
  int hh = (g / (64 * 20)) & 7;
  int b  = g / (64 * 20 * 8);
  int o  = hh * 64 + j;
  const float* wc = WCbc + o * 11;
  const float* vr = V + ((size_t)b * 20 + lc) * 10;
  float s = wc[10];
#pragma unroll
  for (int c = 0; c < 10; c++) s = fmaf(vr[c], wc[c], s);
  vsT[g] = f2bf(s);
}

// ---------------------------------------------------------------------------
// P2c: W_O -> bf16
__global__ void k_wobf(const float* __restrict__ Wo, u16* __restrict__ Wobf){
  int g = blockIdx.x * 256 + threadIdx.x;
  if (g < 512 * 512) Wobf[g] = f2bf(Wo[g]);
}

// ---------------------------------------------------------------------------
// S: per (b,h): on-the-fly Gram operands from LDS f16 y (dot2), double-buffered
//    tiles, 16 waves = 4 row-quads x 4 col-quads. Softmax via 4-way LDS merge.
// LDS map (bytes):
//   0      yq   [2050 x 20]          41000
//   41000  yk   [2050 x 20]          41000   (ends 82000)
//   82000  Al0  [64 x 144]            9216   (epilogue: Atl attn tile)
//   91216  Bl0                        9216
//   100432 Al1                        9216
//   109648 Bl1                        9216   -> total 118864
//   epilogue aliases (y dead): vstl @17408 [32x144], Emax @22016 [4][64]f32,
//                              Esum @23040 [4][64]f32
__launch_bounds__(1024, 1)
__global__ void k_scores(const u32* __restrict__ ypack,
                         const u32* __restrict__ wp1, const float* __restrict__ pb1,
                         const u32* __restrict__ wp2, const float* __restrict__ pb2,
                         const float* __restrict__ prev,
                         const u16* __restrict__ vsT,
                         float* __restrict__ attn_out, float* __restrict__ scores_out,
                         u16* __restrict__ ctx2)
{
  __shared__ uint4 smem_[7429];           // 118864 B
  char* sm  = (char*)smem_;
  char* Al0 = sm + 82000;
  char* Bl0 = sm + 91216;
  char* Al1 = sm + 100432;
  char* Bl1 = sm + 109648;

  int b    = blockIdx.x & (NB - 1);       // 8 h-blocks of same b -> same XCD
  int h    = blockIdx.x >> 7;
  int tid  = threadIdx.x;
  int lane = tid & 63, w = tid >> 6;      // 16 waves
  int rw   = w & 3, cw = w >> 2;          // row-quad, col-quad

  { // stage y (82000 B contiguous per b) as uint4, stride-1 (conflict-free)
    const uint4* src = (const uint4*)(ypack + (size_t)b * 20500);
    uint4* dstl = (uint4*)sm;
    for (int i = tid; i < 5125; i += 1024) dstl[i] = src[i];
  }

  // gen: wave w fills kk in [4w, 4w+4) for one K-tile; packed b64 tile writes
  auto gen = [&](int ktile, char* Ap, char* Bp){
    u32 apk[2] = {0,0}, bpk[2] = {0,0};
#pragma unroll
    for (int m = 0; m < 4; m++){
      int kk = 4 * w + m;
      int k  = ktile * 64 + kk;
      float aval = 0.f, bval = 0.f;
      if (k < LT){
        int base = k * 512 + h * 64;
        int c0 = base / LT;
        int t0 = base - c0 * LT;
        int c0s = __builtin_amdgcn_readfirstlane(c0);
        int t0s = __builtin_amdgcn_readfirstlane(t0);
        int t  = t0s + lane;
        int tw = (t >= LT) ? (t - LT) : t;
        const u32* yq = (const u32*)(sm + tw * 20);
        const u32* yk = (const u32*)(sm + 41000 + tw * 20);
        u32 qa[5], ka[5];
#pragma unroll
        for (int u = 0; u < 5; u++){ qa[u] = yq[u]; ka[u] = yk[u]; }
        if (t0s <= LT - 64){                 // no c-boundary inside chunk (97%)
          aval = pb1[c0s]; bval = pb2[c0s];
          const u32* w1 = wp1 + c0s * 5;
          const u32* w2 = wp2 + c0s * 5;
#pragma unroll
          for (int u = 0; u < 5; u++){
            aval = dot2p(qa[u], w1[u], aval);
            bval = dot2p(ka[u], w2[u], bval);
          }
        } else {
          int c1s = c0s + 1;                 // never exceeds 511
          bool wb = (t >= LT);
          aval = wb ? pb1[c1s] : pb1[c0s];
          bval = wb ? pb2[c1s] : pb2[c0s];
#pragma unroll
          for (int u = 0; u < 5; u++){
            u32 w1u = wb ? wp1[c1s*5 + u] : wp1[c0s*5 + u];
            u32 w2u = wb ? wp2[c1s*5 + u] : wp2[c0s*5 + u];
            aval = dot2p(qa[u], w1u, aval);
            bval = dot2p(ka[u], w2u, bval);
          }
        }
      }
      apk[m >> 1] |= ((u32)f2bf(aval)) << ((m & 1) * 16);
      bpk[m >> 1] |= ((u32)f2bf(bval)) << ((m & 1) * 16);
    }
    *(uint2*)(Ap + lane * 144 + 8 * w) = make_uint2(apk[0], apk[1]);
    *(uint2*)(Bp + lane * 144 + 8 * w) = make_uint2(bpk[0], bpk[1]);
  };

  __syncthreads();                          // y staged
  gen(0, Al0, Bl0);
  __syncthreads();

  f32x4 acc = {0,0,0,0};
  char* Ac = Al0; char* Bc = Bl0; char* An = Al1; char* Bn = Bl1;

  for (int kt = 0; kt < 33; kt++){
    if (kt < 32) gen(kt + 1, An, Bn);
    {
      const char* pa = Ac + (16*rw + (lane & 15)) * 144 + ((lane >> 4) * 16);
      const char* pb = Bc + (16*cw + (lane & 15)) * 144 + ((lane >> 4) * 16);
#pragma unroll
      for (int ks = 0; ks < 2; ks++){
        s16x8 av = *(const s16x8*)(pa + ks * 64);
        s16x8 bv = *(const s16x8*)(pb + ks * 64);
        acc = __builtin_amdgcn_mfma_f32_16x16x32_bf16(av, bv, acc, 0, 0, 0);
      }
    }
    char* ts;
    ts = Ac; Ac = An; An = ts;
    ts = Bc; Bc = Bn; Bn = ts;
    __syncthreads();
  }

  // ---- epilogue (y region dead)
  char*  vstl = sm + 17408;                 // [32][144] bf16
  float* Emax = (float*)(sm + 22016);       // [4][64]
  float* Esum = (float*)(sm + 23040);       // [4][64]
  char*  Atl  = Al0;                        // attn bf16 tile [64][144]

  if (tid < 256){                           // stage v_s^T rows (20 real, pad 32)
    int row = tid >> 3, c8 = tid & 7;
    uint4 v = make_uint4(0, 0, 0, 0);
    if (row < 20)
      v = *(const uint4*)((const char*)vsT + ((size_t)(b*NH + h)) * 2560 + row * 128 + c8 * 16);
    *(uint4*)(vstl + row * 144 + c8 * 16) = v;
  }

  int ib = 16 * rw + ((lane >> 4) << 2);    // C/D row base
  int jb = 16 * cw + (lane & 15);           // C/D col (this wave's quarter)
  const float* prevb = prev       + ((size_t)(b*NH + h)) * 4096;
  float*       scob  = scores_out + ((size_t)(b*NH + h)) * 4096;
  float*       atob  = attn_out   + ((size_t)(b*NH + h)) * 4096;

  float sc[4];
#pragma unroll
  for (int r = 0; r < 4; r++)
    sc[r] = acc[r] * 0.125f + prevb[(ib + r) * 64 + jb];

  // per-row partial max over this wave's 16 cols
  float pm[4];
#pragma unroll
  for (int r = 0; r < 4; r++) pm[r] = sc[r];
#pragma unroll
  for (int s = 1; s < 16; s <<= 1)
#pragma unroll
    for (int r = 0; r < 4; r++) pm[r] = fmaxf(pm[r], __shfl_xor(pm[r], s, 64));
  if ((lane & 15) == 0){
#pragma unroll
    for (int r = 0; r < 4; r++) Emax[cw * 64 + ib + r] = pm[r];
  }
  // scores to global while waiting
#pragma unroll
  for (int r = 0; r < 4; r++)
    scob[(ib + r) * 64 + jb] = sc[r];
  __syncthreads();

  float e[4], ps[4];
#pragma unroll
  for (int r = 0; r < 4; r++){
    int i = ib + r;
    float m4 = fmaxf(fmaxf(Emax[i], Emax[64 + i]), fmaxf(Emax[128 + i], Emax[192 + i]));
    e[r] = __expf(sc[r] - m4);
    ps[r] = e[r];
  }
#pragma unroll
  for (int s = 1; s < 16; s <<= 1)
#pragma unroll
    for (int r = 0; r < 4; r++) ps[r] += __shfl_xor(ps[r], s, 64);
  if ((lane & 15) == 0){
#pragma unroll
    for (int r = 0; r < 4; r++) Esum[cw * 64 + ib + r] = ps[r];
  }
  __syncthreads();

#pragma unroll
  for (int r = 0; r < 4; r++){
    int i = ib + r;
    float inv = 1.0f / (Esum[i] + Esum[64 + i] + Esum[128 + i] + Esum[192 + i]);
    float at = e[r] * inv;
    atob[i * 64 + jb] = at;
    *(u16*)(Atl + i * 144 + jb * 2) = f2bf(at);
  }
  __syncthreads();

  // ---- context = attn @ v_s : waves 0..7 -> rows [16rw..+16), v cols [16cw..+16)
  if (w < 8){
    f32x4 ca = {0,0,0,0};
    const char* pa = Atl  + (16*rw + (lane & 15)) * 144 + ((lane >> 4) * 16);
    const char* pv = vstl + (16*(w >> 2) + (lane & 15)) * 144 + ((lane >> 4) * 16);
#pragma unroll
    for (int ks = 0; ks < 2; ks++){
      s16x8 av = *(const s16x8*)(pa + ks * 64);
      s16x8 bv = *(const s16x8*)(pv + ks * 64);
      ca = __builtin_amdgcn_mfma_f32_16x16x32_bf16(av, bv, ca, 0, 0, 0);
    }
    u16* ctxb = ctx2 + (size_t)b * 10240;
    int lc = 16 * (w >> 2) + (lane & 15);
    if (lc < 20){
#pragma unroll
      for (int r = 0; r < 4; r++)
        ctxb[(ib + r) * 160 + h * 20 + lc] = f2bf(ca[r]);
    }
  }
}

// ---------------------------------------------------------------------------
// O: output[b] = ctx2[b] (20x512, pad 32) @ W_O^T via MFMA, K=512
__launch_bounds__(256)
__global__ void k_out(const u16* __restrict__ ctx2, const u16* __restrict__ Wobf,
                      float* __restrict__ outp)
{
  __shared__ u16 ctxl[32 * 520];
  int b = blockIdx.x, tid = threadIdx.x;
  for (int idx = tid; idx < 2048; idx += 256){
    int row = idx >> 6, c8 = idx & 63;
    uint4 v = make_uint4(0, 0, 0, 0);
    if (row < 20)
      v = *(const uint4*)((const char*)ctx2 + (size_t)b * 20480 + row * 1024 + c8 * 16);
    *(uint4*)((char*)ctxl + row * 1040 + c8 * 16) = v;
  }
  __syncthreads();
  int lane = tid & 63, w = tid >> 6;
  f32x4 acc[2][8];
#pragma unroll
  for (int m2 = 0; m2 < 2; m2++)
#pragma unroll
    for (int n = 0; n < 8; n++) acc[m2][n] = (f32x4){0,0,0,0};

  for (int ks = 0; ks < 16; ks++){
    s16x8 a0 = *(const s16x8*)((char*)ctxl + (lane & 15) * 1040        + ks * 64 + ((lane >> 4) * 16));
    s16x8 a1 = *(const s16x8*)((char*)ctxl + (16 + (lane & 15)) * 1040 + ks * 64 + ((lane >> 4) * 16));
#pragma unroll
    for (int n = 0; n < 8; n++){
      int d = w * 128 + n * 16 + (lane & 15);
      s16x8 bb = *(const s16x8*)((const char*)Wobf + (size_t)d * 1024 + ks * 64 + ((lane >> 4) * 16));
      acc[0][n] = __builtin_amdgcn_mfma_f32_16x16x32_bf16(a0, bb, acc[0][n], 0, 0, 0);
      acc[1][n] = __builtin_amdgcn_mfma_f32_16x16x32_bf16(a1, bb, acc[1][n], 0, 0, 0);
    }
  }
  float* ob = outp + (size_t)b * 10240;
#pragma unroll
  for (int m2 = 0; m2 < 2; m2++){
    int lp0 = m2 * 16 + ((lane >> 4) << 2);
    if (lp0 >= 20) continue;
#pragma unroll
    for (int n = 0; n < 8; n++){
      int d = w * 128 + n * 16 + (lane & 15);
#pragma unroll
      for (int r = 0; r < 4; r++){
        int lp = lp0 + r;
        if (lp < 20) ob[lp * 512 + d] = acc[m2][n][r];
      }
    }
  }
}

// ---------------------------------------------------------------------------
extern "C" void kernel_launch(void* const* d_in, const int* in_sizes, int n_in,
                              void* d_out, int out_size, void* d_ws, size_t ws_size,
                              hipStream_t stream)
{
  (void)in_sizes; (void)n_in; (void)out_size; (void)ws_size;
  const float* Q      = (const float*)d_in[0];
  const float* K      = (const float*)d_in[1];
  const float* V      = (const float*)d_in[2];
  const float* prev   = (const float*)d_in[3];
  const float* c1w    = (const float*)d_in[4];
  const float* c1b    = (const float*)d_in[5];
  const float* c1pw   = (const float*)d_in[6];
  const float* c1pb   = (const float*)d_in[7];
  const float* c2w    = (const float*)d_in[8];
  const float* c2b    = (const float*)d_in[9];
  const float* c2pw   = (const float*)d_in[10];
  const float* c2pb   = (const float*)d_in[11];
  const float* vfw    = (const float*)d_in[12];
  const float* vfb    = (const float*)d_in[13];
  const float* Wv     = (const float*)d_in[14];
  const float* Wo     = (const float*)d_in[15];

  char* ws = (char*)d_ws;
  u32*   ypack = (u32*)(ws + 0);            // 128 * 82000 = 10,496,000 B
  u32*   wp1   = (u32*)(ws + 10496000);     //     10,240 B
  u32*   wp2   = (u32*)(ws + 10506240);     //     10,240 B
  float* WCbc  = (float*)(ws + 10516480);   //     22,528 B
  u16*   vsT   = (u16*)(ws + 10539008);     //  2,621,440 B
  u16*   Wobf  = (u16*)(ws + 13160448);     //    524,288 B
  u16*   ctx2  = (u16*)(ws + 13684736);     //  2,621,440 B (total ~16.3 MB)

  float* outp     = (float*)d_out;
  float* attn_o   = outp + 1310720;
  float* scores_o = outp + 5505024;

  k_pack_y<<<dim3(1025), dim3(256), 0, stream>>>(Q, K, c1w, c1b, c2w, c2b, ypack);
  k_wpack <<<dim3(10),   dim3(256), 0, stream>>>(c1pw, c2pw, wp1, wp2);
  k_wc    <<<dim3(22),   dim3(256), 0, stream>>>(Wv, vfw, vfb, WCbc);
  k_vst   <<<dim3(5120), dim3(256), 0, stream>>>(V, WCbc, vsT);
  k_wobf  <<<dim3(1024), dim3(256), 0, stream>>>(Wo, Wobf);
  k_scores<<<dim3(1024), dim3(1024), 0, stream>>>(ypack, wp1, c1pb, wp2, c2pb,
                                                  prev, vsT, attn_o, scores_o, ctx2);
  k_out   <<<dim3(128),  dim3(256), 0, stream>>>(ctx2, Wobf, outp);
}